// Round 1
// baseline (7553.944 us; speedup 1.0000x reference)
//
#include <hip/hip_runtime.h>
#include <hip/hip_bf16.h>

// TemporalDecoder: B=2048, LATENT=128, HIDDEN=512, DEPTH=2, NUMF=128, T=128
// Strategy: bf16 MFMA (16x16x32) for all contractions, fp32 master h-state,
// fp32 gate math. gi0 precomputed (e is constant across time).
// Outputs: [tn(2048*128*128) | u(2048*128) | m(2048*128*128) | seq(2048 as float)]

using bf16 = __hip_bfloat16;
typedef __attribute__((ext_vector_type(8))) short short8;  // 8 bf16 = 4 VGPR
typedef __attribute__((ext_vector_type(4))) float f32x4;

#define MFMA(a, b, c) __builtin_amdgcn_mfma_f32_16x16x32_bf16((a), (b), (c), 0, 0, 0)

#define OFF_U 33554432
#define OFF_M 33816576
#define OFF_S 67371008

__device__ __forceinline__ void gld16(const void* g, void* l) {
  __builtin_amdgcn_global_load_lds(
      (const __attribute__((address_space(1))) unsigned int*)g,
      (__attribute__((address_space(3))) unsigned int*)l, 16, 0, 0);
}

__device__ __forceinline__ float sigm(float x) { return 1.f / (1.f + __expf(-x)); }

// Read a 16x32 (rows x k) MFMA fragment from an LDS tile with XOR swizzle.
// tile layout: [rows][rowbytes], logical byte = row*rowbytes + k*2,
// physical = logical ^ ((row&7)<<4).  (staging applied the same XOR on source)
__device__ __forceinline__ short8 frag_ld(const char* tile, int r0, int kk, int lane, int rowbytes) {
  int row = r0 + (lane & 15);
  int off = row * rowbytes + ((kk + ((lane >> 4) << 3)) << 1);
  off ^= (row & 7) << 4;
  return *(const short8*)(tile + off);
}

__global__ void cvtk(const float* __restrict__ s, bf16* __restrict__ d, int n) {
  int i = blockIdx.x * 256 + threadIdx.x;
  if (i < n) d[i] = __float2bfloat16(s[i]);
}

__global__ void initk(int* a, int* l) {
  int i = blockIdx.x * 256 + threadIdx.x;
  a[i] = 1;
  l[i] = 0;
}

__global__ void seqw(const int* __restrict__ lens, float* __restrict__ out) {
  int i = blockIdx.x * 256 + threadIdx.x;
  out[OFF_S + i] = (float)lens[i];
}

// ---------------------------------------------------------------------------
// Plain GEMM: C[2048, N] = A[2048, K](bf16 rm) @ Bw[N, K](bf16 rm)^T + bias
// BM=128, BN=64, BK=64. 256 thr = 4 waves (2x2), wave tile 64x32.
// MODE 0: write fp32 to Of (stride N)          [gi0 / gh1]
// MODE 1: leaky_relu 0.2 -> bf16 Ob (stride512) [fc1]
// MODE 2: h0 view-scatter to (Of,Ob)=hA, (Of2,Ob2)=hB  [fc2, N=1024]
// ---------------------------------------------------------------------------
template <int MODE>
__global__ __launch_bounds__(256) void gemm_plain(
    const bf16* __restrict__ A, const bf16* __restrict__ Bw,
    const float* __restrict__ bias,
    float* __restrict__ Of, bf16* __restrict__ Ob,
    float* __restrict__ Of2, bf16* __restrict__ Ob2,
    int N, int K) {
  __shared__ char smem[2][24576];  // A 16K + B 8K per buffer
  const int tid = threadIdx.x, lane = tid & 63, wave = tid >> 6;
  const int wm = wave >> 1, wn = wave & 1;
  const int bn = blockIdx.x, bm = blockIdx.y;
  const int ldab = K * 2;
  const char* Ab = (const char*)A + (size_t)bm * 128 * ldab;
  const char* Bb = (const char*)Bw + (size_t)bn * 64 * ldab;

  f32x4 acc[4][2] = {};
  const int KT = K >> 6;

  auto stage = [&](int kt, int bi) {
    char* ld = smem[bi];
    const char* Asrc = Ab + kt * 128;
#pragma unroll
    for (int c2 = 0; c2 < 4; ++c2) {
      int c = wave + c2 * 4;
      int p = c * 1024 + lane * 16;
      int row = p >> 7;
      int l = (p & 127) ^ ((row & 7) << 4);
      gld16(Asrc + (size_t)row * ldab + l, ld + c * 1024);
    }
    const char* Bsrc = Bb + kt * 128;
#pragma unroll
    for (int c2 = 0; c2 < 2; ++c2) {
      int c = wave + c2 * 4;
      int p = c * 1024 + lane * 16;
      int row = p >> 7;
      int l = (p & 127) ^ ((row & 7) << 4);
      gld16(Bsrc + (size_t)row * ldab + l, ld + 16384 + c * 1024);
    }
  };

  stage(0, 0);
  __syncthreads();
  for (int kt = 0; kt < KT; ++kt) {
    int cur = kt & 1;
    if (kt + 1 < KT) stage(kt + 1, cur ^ 1);
    const char* ldsA = smem[cur];
    const char* ldsB = smem[cur] + 16384;
#pragma unroll
    for (int kh = 0; kh < 2; ++kh) {
      int kk = kh * 32;
      short8 a[4], b[2];
#pragma unroll
      for (int mi = 0; mi < 4; ++mi) a[mi] = frag_ld(ldsA, wm * 64 + mi * 16, kk, lane, 128);
#pragma unroll
      for (int nj = 0; nj < 2; ++nj) b[nj] = frag_ld(ldsB, wn * 32 + nj * 16, kk, lane, 128);
#pragma unroll
      for (int mi = 0; mi < 4; ++mi)
#pragma unroll
        for (int nj = 0; nj < 2; ++nj) acc[mi][nj] = MFMA(a[mi], b[nj], acc[mi][nj]);
    }
    __syncthreads();
  }

#pragma unroll
  for (int mi = 0; mi < 4; ++mi)
#pragma unroll
    for (int nj = 0; nj < 2; ++nj) {
      int col = bn * 64 + wn * 32 + nj * 16 + (lane & 15);
      float bc = bias[col];
#pragma unroll
      for (int ii = 0; ii < 4; ++ii) {
        int row = bm * 128 + wm * 64 + mi * 16 + ((lane >> 4) << 2) + ii;
        float v = acc[mi][nj][ii] + bc;
        if constexpr (MODE == 0) {
          Of[(size_t)row * N + col] = v;
        } else if constexpr (MODE == 1) {
          v = v > 0.f ? v : 0.2f * v;
          Ob[row * 512 + col] = __float2bfloat16(v);
        } else {
          // h0_flat[2048,1024].reshape(2,B,H): d=row>>10, b=2*(row&1023)+(col>=512), j=col&511
          int d = row >> 10, rr = row & 1023;
          int b = 2 * rr + (col >> 9), j = col & 511;
          float* of = d ? Of2 : Of;
          bf16* ob = d ? Ob2 : Ob;
          of[b * 512 + j] = v;
          ob[b * 512 + j] = __float2bfloat16(v);
        }
      }
    }
}

// ---------------------------------------------------------------------------
// Fused GEMM + GRU cell.  Output f (fresh) and masked next state.
// GEMM side: Ag[2048,512] @ W[1536,512]^T, three gate column-groups
// accumulated simultaneously (acc[gate]); other side read from buf (pre-biased
// [2048,1536]).  GEMM_IS_H: GEMM computes h-side (layer0);
// else GEMM computes i-side (layer1, buf=gh1).
// BM=64, BN=64; 4 waves 2x2; wave tile 32x32 per gate.
// ---------------------------------------------------------------------------
template <bool GEMM_IS_H>
__global__ __launch_bounds__(256) void gru_fuse(
    const bf16* __restrict__ Ag, const bf16* __restrict__ W,
    const float* __restrict__ bias, const float* __restrict__ buf,
    const float* __restrict__ Hprev, const int* __restrict__ active,
    bf16* __restrict__ Fout, float* __restrict__ Hnf, bf16* __restrict__ Hnb) {
  __shared__ char smem[2][32768];  // A 8K + B 3x8K per buffer
  const int tid = threadIdx.x, lane = tid & 63, wave = tid >> 6;
  const int wm = wave >> 1, wn = wave & 1;
  const int bn = blockIdx.x, bm = blockIdx.y;  // grid (8, 32)
  const char* Ab = (const char*)Ag + (size_t)bm * 64 * 1024;

  f32x4 acc[3][2][2] = {};

  auto stage = [&](int kt, int bi) {
    char* ld = smem[bi];
    const char* Asrc = Ab + kt * 128;
#pragma unroll
    for (int c2 = 0; c2 < 2; ++c2) {
      int c = wave + c2 * 4;  // 0..7
      int p = c * 1024 + lane * 16;
      int row = p >> 7;
      int l = (p & 127) ^ ((row & 7) << 4);
      gld16(Asrc + (size_t)row * 1024 + l, ld + c * 1024);
    }
#pragma unroll
    for (int c2 = 0; c2 < 6; ++c2) {
      int c = wave + c2 * 4;  // 0..23 ; gate g = c>>3, chunk r = c&7
      int g = c >> 3, r = c & 7;
      int p = r * 1024 + lane * 16;
      int row = p >> 7;
      int l = (p & 127) ^ ((row & 7) << 4);
      gld16((const char*)W + ((size_t)(g * 512) + bn * 64 + row) * 1024 + kt * 128 + l,
            ld + 8192 + c * 1024);
    }
  };

  stage(0, 0);
  __syncthreads();
  for (int kt = 0; kt < 8; ++kt) {
    int cur = kt & 1;
    if (kt < 7) stage(kt + 1, cur ^ 1);
    const char* ldsA = smem[cur];
    const char* ldsB = smem[cur] + 8192;
#pragma unroll
    for (int kh = 0; kh < 2; ++kh) {
      int kk = kh * 32;
      short8 a[2], b[3][2];
#pragma unroll
      for (int mi = 0; mi < 2; ++mi) a[mi] = frag_ld(ldsA, wm * 32 + mi * 16, kk, lane, 128);
#pragma unroll
      for (int g = 0; g < 3; ++g)
#pragma unroll
        for (int nj = 0; nj < 2; ++nj)
          b[g][nj] = frag_ld(ldsB + g * 8192, wn * 32 + nj * 16, kk, lane, 128);
#pragma unroll
      for (int g = 0; g < 3; ++g)
#pragma unroll
        for (int mi = 0; mi < 2; ++mi)
#pragma unroll
          for (int nj = 0; nj < 2; ++nj)
            acc[g][mi][nj] = MFMA(a[mi], b[g][nj], acc[g][mi][nj]);
    }
    __syncthreads();
  }

#pragma unroll
  for (int mi = 0; mi < 2; ++mi)
#pragma unroll
    for (int nj = 0; nj < 2; ++nj) {
      int col = bn * 64 + wn * 32 + nj * 16 + (lane & 15);
      float br = bias[col], bz = bias[512 + col], bnn = bias[1024 + col];
#pragma unroll
      for (int ii = 0; ii < 4; ++ii) {
        int row = bm * 64 + wm * 32 + mi * 16 + ((lane >> 4) << 2) + ii;
        const float* bro = buf + (size_t)row * 1536;
        float gr = acc[0][mi][nj][ii] + br;
        float gz = acc[1][mi][nj][ii] + bz;
        float gn = acc[2][mi][nj][ii] + bnn;
        float xr = bro[col], xz = bro[512 + col], xn = bro[1024 + col];
        float r_ = sigm(gr + xr);
        float z_ = sigm(gz + xz);
        float n_;
        if constexpr (GEMM_IS_H)
          n_ = tanhf(xn + r_ * gn);  // n = tanh(i_n + r*h_n), h-side in GEMM
        else
          n_ = tanhf(gn + r_ * xn);  // i-side in GEMM
        float hp = Hprev[row * 512 + col];
        float f = (1.f - z_) * n_ + z_ * hp;
        Fout[row * 512 + col] = __float2bfloat16(f);
        float hn = active[row] ? f : hp;
        Hnf[row * 512 + col] = hn;
        Hnb[row * 512 + col] = __float2bfloat16(hn);
      }
    }
}

// ---------------------------------------------------------------------------
// Output head: z[16,320] = F2[16 rows,512] @ Wout[320,512]^T ; tn=sig(z0:128),
// u=sig(lrelu(z128:192)@wt2+bt2), m=z192:320+bm ; stop/active/lens update.
// Block: 16 rows, 4 waves each owning 80 cols (5 frags). A staged to LDS once;
// B read straight from L2 (Wout is 320KB bf16, fully cache-resident).
// ---------------------------------------------------------------------------
__global__ __launch_bounds__(256) void outproj(
    const bf16* __restrict__ F2, const bf16* __restrict__ Wo,
    const float* __restrict__ bv, const float* __restrict__ bt1,
    const float* __restrict__ bm_, const float* __restrict__ wt2,
    const float* __restrict__ bt2,
    int* __restrict__ active, int* __restrict__ lens,
    float* __restrict__ out, int t) {
  __shared__ char sA[16384];
  __shared__ float red[16][68];  // padded: avoid 16-way conflict in u-reduction
  __shared__ unsigned stopf[16];
  const int tid = threadIdx.x, lane = tid & 63, wave = tid >> 6;
  const int brow = blockIdx.x * 16;

  if (tid < 16) stopf[tid] = 0;

#pragma unroll
  for (int c2 = 0; c2 < 4; ++c2) {
    int c = wave + c2 * 4;  // row 0..15 (1024B per row = one chunk)
    int p = lane * 16;
    int l = p ^ ((c & 7) << 4);
    gld16((const char*)F2 + (size_t)(brow + c) * 1024 + l, sA + c * 1024);
  }
  __syncthreads();

  f32x4 acc[5] = {};
#pragma unroll 4
  for (int k0 = 0; k0 < 512; k0 += 32) {
    short8 a = frag_ld(sA, 0, k0, lane, 1024);
#pragma unroll
    for (int nf = 0; nf < 5; ++nf) {
      int col = wave * 80 + nf * 16 + (lane & 15);
      short8 b = *(const short8*)((const char*)Wo + (size_t)col * 1024 +
                                  ((k0 + ((lane >> 4) << 3)) << 1));
      acc[nf] = MFMA(a, b, acc[nf]);
    }
  }

#pragma unroll
  for (int nf = 0; nf < 5; ++nf) {
    int col = wave * 80 + nf * 16 + (lane & 15);
#pragma unroll
    for (int ii = 0; ii < 4; ++ii) {
      int r = ((lane >> 4) << 2) + ii;
      int b = brow + r;
      float v = acc[nf][ii];
      if (col < 128) {
        out[(size_t)b * 16384 + t * 128 + col] = sigm(v + bv[col]);
      } else if (col < 192) {
        float x = v + bt1[col - 128];
        red[r][col - 128] = x > 0.f ? x : 0.2f * x;
      } else {
        float m = v + bm_[col - 192];
        out[OFF_M + (size_t)b * 16384 + t * 128 + (col - 192)] = m;
        if (m >= 0.f) atomicOr(&stopf[r], 1u);  // any m>=0 => not stopped
      }
    }
  }
  __syncthreads();
  if (tid < 16) {
    int b = brow + tid;
    float s = bt2[0];
    for (int c = 0; c < 64; ++c) s += red[tid][c] * wt2[c];
    out[OFF_U + (size_t)b * 128 + t] = sigm(s);
    int act = active[b];
    lens[b] += act;
    active[b] = act & (stopf[tid] ? 1 : 0);  // stop iff all m<0 (stopf==0)
  }
}

extern "C" void kernel_launch(void* const* d_in, const int* in_sizes, int n_in,
                              void* d_out, int out_size, void* d_ws, size_t ws_size,
                              hipStream_t stream) {
  const float* e = (const float*)d_in[0];
  const float* fc1w = (const float*)d_in[1];
  const float* fc1b = (const float*)d_in[2];
  const float* fc2w = (const float*)d_in[3];
  const float* fc2b = (const float*)d_in[4];
  const float* wih0 = (const float*)d_in[5];
  const float* whh0 = (const float*)d_in[6];
  const float* bih0 = (const float*)d_in[7];
  const float* bhh0 = (const float*)d_in[8];
  const float* wih1 = (const float*)d_in[9];
  const float* whh1 = (const float*)d_in[10];
  const float* bih1 = (const float*)d_in[11];
  const float* bhh1 = (const float*)d_in[12];
  const float* wv = (const float*)d_in[13];
  const float* bv = (const float*)d_in[14];
  const float* wt1 = (const float*)d_in[15];
  const float* bt1 = (const float*)d_in[16];
  const float* wt2 = (const float*)d_in[17];
  const float* bt2 = (const float*)d_in[18];
  const float* wm = (const float*)d_in[19];
  const float* bmb = (const float*)d_in[20];
  float* out = (float*)d_out;

  char* p = (char*)d_ws;
  auto carve = [&](size_t bytes) {
    char* r = p;
    p += (bytes + 255) & ~(size_t)255;
    return r;
  };
  bf16* e_b = (bf16*)carve(2048 * 128 * 2);
  bf16* t1_b = (bf16*)carve(2048 * 512 * 2);
  bf16* wfc1b = (bf16*)carve(512 * 128 * 2);
  bf16* wfc2b = (bf16*)carve(1024 * 512 * 2);
  bf16* wih0b = (bf16*)carve(1536 * 128 * 2);
  bf16* whh0b = (bf16*)carve(1536 * 512 * 2);
  bf16* wih1b = (bf16*)carve(1536 * 512 * 2);
  bf16* whh1b = (bf16*)carve(1536 * 512 * 2);
  bf16* woutb = (bf16*)carve(320 * 512 * 2);
  float* gi0 = (float*)carve((size_t)2048 * 1536 * 4);
  float* gbuf = (float*)carve((size_t)2048 * 1536 * 4);
  float* hAf[2] = {(float*)carve(2048 * 512 * 4), (float*)carve(2048 * 512 * 4)};
  bf16* hAb[2] = {(bf16*)carve(2048 * 512 * 2), (bf16*)carve(2048 * 512 * 2)};
  float* hBf[2] = {(float*)carve(2048 * 512 * 4), (float*)carve(2048 * 512 * 4)};
  bf16* hBb[2] = {(bf16*)carve(2048 * 512 * 2), (bf16*)carve(2048 * 512 * 2)};
  bf16* f1b = (bf16*)carve(2048 * 512 * 2);
  bf16* f2b = (bf16*)carve(2048 * 512 * 2);
  int* act = (int*)carve(2048 * 4);
  int* lens = (int*)carve(2048 * 4);

  auto cvt = [&](const float* s, bf16* d, int n) {
    cvtk<<<dim3((n + 255) / 256), dim3(256), 0, stream>>>(s, d, n);
  };
  cvt(e, e_b, 2048 * 128);
  cvt(fc1w, wfc1b, 512 * 128);
  cvt(fc2w, wfc2b, 1024 * 512);
  cvt(wih0, wih0b, 1536 * 128);
  cvt(whh0, whh0b, 1536 * 512);
  cvt(wih1, wih1b, 1536 * 512);
  cvt(whh1, whh1b, 1536 * 512);
  cvt(wv, woutb, 128 * 512);
  cvt(wt1, woutb + 128 * 512, 64 * 512);
  cvt(wm, woutb + 192 * 512, 128 * 512);
  initk<<<dim3(8), dim3(256), 0, stream>>>(act, lens);

  // h0 init: t1 = lrelu(e@fc1^T+b); h0 = t1@fc2^T+b viewed (2,B,H)
  gemm_plain<1><<<dim3(8, 16), dim3(256), 0, stream>>>(
      e_b, wfc1b, fc1b, nullptr, t1_b, nullptr, nullptr, 512, 128);
  gemm_plain<2><<<dim3(16, 16), dim3(256), 0, stream>>>(
      t1_b, wfc2b, fc2b, hAf[0], hAb[0], hBf[0], hBb[0], 1024, 512);
  // gi0 = e @ w_ih0^T + b_ih0   (constant over time)
  gemm_plain<0><<<dim3(24, 16), dim3(256), 0, stream>>>(
      e_b, wih0b, bih0, gi0, nullptr, nullptr, nullptr, 1536, 128);

  for (int t = 0; t < 128; ++t) {
    int cur = t & 1, nxt = cur ^ 1;
    // layer 0: GEMM h-side (hA @ w_hh0^T), i-side from gi0
    gru_fuse<true><<<dim3(8, 32), dim3(256), 0, stream>>>(
        hAb[cur], whh0b, bhh0, gi0, hAf[cur], act, f1b, hAf[nxt], hAb[nxt]);
    // gh1 = hB @ w_hh1^T + b_hh1
    gemm_plain<0><<<dim3(24, 16), dim3(256), 0, stream>>>(
        hBb[cur], whh1b, bhh1, gbuf, nullptr, nullptr, nullptr, 1536, 512);
    // layer 1: GEMM i-side (f1 @ w_ih1^T), h-side from gbuf
    gru_fuse<false><<<dim3(8, 32), dim3(256), 0, stream>>>(
        f1b, wih1b, bih1, gbuf, hBf[cur], act, f2b, hBf[nxt], hBb[nxt]);
    // heads + stop/active/lens
    outproj<<<dim3(128), dim3(256), 0, stream>>>(
        f2b, woutb, bv, bt1, bmb, wt2, bt2, act, lens, out, t);
  }
  seqw<<<dim3(8), dim3(256), 0, stream>>>(lens, out);
}

// Round 2
// 5976.426 us; speedup vs baseline: 1.2640x; 1.2640x over previous
//
#include <hip/hip_runtime.h>
#include <hip/hip_bf16.h>

// TemporalDecoder: B=2048, LATENT=128, HIDDEN=512, DEPTH=2, NUMF=128, T=128
// Round 2: concat-K GRU GEMMs (A=[x|h], W=[w_ih|w_hh]) with split n-gate
// accumulators. 3 kernels/step: L0 (K=640), L1 (K=1024), outproj.
// bf16 MFMA 16x16x32, fp32 master h-state, fp32 gate math.

using bf16 = __hip_bfloat16;
typedef __attribute__((ext_vector_type(8))) short short8;  // 8 bf16
typedef __attribute__((ext_vector_type(4))) float f32x4;

#define MFMA(a, b, c) __builtin_amdgcn_mfma_f32_16x16x32_bf16((a), (b), (c), 0, 0, 0)

#define OFF_U 33554432
#define OFF_M 33816576
#define OFF_S 67371008

__device__ __forceinline__ void gld16(const void* g, void* l) {
  __builtin_amdgcn_global_load_lds(
      (const __attribute__((address_space(1))) unsigned int*)g,
      (__attribute__((address_space(3))) unsigned int*)l, 16, 0, 0);
}

__device__ __forceinline__ float sigm(float x) { return 1.f / (1.f + __expf(-x)); }

// Read a 16x32 MFMA fragment from a swizzled LDS tile ([rows][rowbytes],
// phys = logical ^ ((row&7)<<4)).
__device__ __forceinline__ short8 frag_ld(const char* tile, int r0, int kk, int lane, int rowbytes) {
  int row = r0 + (lane & 15);
  int off = row * rowbytes + ((kk + ((lane >> 4) << 3)) << 1);
  off ^= (row & 7) << 4;
  return *(const short8*)(tile + off);
}

// Stage one 1KB chunk (8 rows x 128B) global->LDS with inverse-swizzled source.
// dst = wave-uniform LDS base (linear lane*16 fill). src row stride ldb bytes.
__device__ __forceinline__ void stage_rows(const char* src_base, int ldb, int kbyte,
                                           int row0, char* dst, int lane) {
  int r = lane >> 3;                      // row within chunk 0..7 (== row&7)
  int l = ((lane & 7) ^ r) << 4;          // swizzled within-row byte
  gld16(src_base + (size_t)(row0 + r) * ldb + kbyte + l, dst);
}

// ------------------------------- setup kernels -----------------------------
__global__ void cvtk(const float* __restrict__ s, bf16* __restrict__ d, int n) {
  int i = blockIdx.x * 256 + threadIdx.x;
  if (i < n) d[i] = __float2bfloat16(s[i]);
}

__global__ void initk(int* a, int* l) {
  int i = blockIdx.x * 256 + threadIdx.x;
  a[i] = 1;
  l[i] = 0;
}

// e -> X0[0][:,0:128] and X0[1][:,0:128] (bf16), row stride 640
__global__ void e_fill(const float* __restrict__ e, bf16* __restrict__ x0a,
                       bf16* __restrict__ x0b) {
  int i = blockIdx.x * 256 + threadIdx.x;  // 2048*128
  int r = i >> 7, c = i & 127;
  bf16 v = __float2bfloat16(e[i]);
  x0a[r * 640 + c] = v;
  x0b[r * 640 + c] = v;
}

// Wcat[1536][kx+512] = [w_ih row | w_hh row], f32->bf16
__global__ void catk(const float* __restrict__ wih, const float* __restrict__ whh,
                     bf16* __restrict__ dst, int kx, int total) {
  int i = blockIdx.x * 256 + threadIdx.x;
  if (i >= total) return;
  int ktot = kx + 512;
  int r = i / ktot, c = i - r * ktot;
  float v = (c < kx) ? wih[r * kx + c] : whh[r * 512 + (c - kx)];
  dst[i] = __float2bfloat16(v);
}

// ---------------------------------------------------------------------------
// Setup GEMM: C[2048,N] = A[2048,K]@Bw[N,K]^T + bias. BM=128 BN=64 BK=64.
// MODE 1: leaky_relu -> bf16 Ob stride 512                       [fc1]
// MODE 2: h0 view-scatter -> hAf0/x0h (d=0), hBf0/x1h (d=1)      [fc2]
// ---------------------------------------------------------------------------
template <int MODE>
__global__ __launch_bounds__(256) void gemm_plain(
    const bf16* __restrict__ A, const bf16* __restrict__ Bw,
    const float* __restrict__ bias,
    bf16* __restrict__ Ob,                      // MODE1 out / MODE2 x0h
    float* __restrict__ Of, float* __restrict__ Of2, bf16* __restrict__ Ob2,
    int K, int lda_b, int ldb_b) {
  __shared__ char smem[2][24576];  // A 16K + B 8K
  const int tid = threadIdx.x, lane = tid & 63, wave = tid >> 6;
  const int wm = wave >> 1, wn = wave & 1;
  const int bn = blockIdx.x, bm = blockIdx.y;
  const char* Ab = (const char*)A + (size_t)bm * 128 * lda_b;
  const char* Bb = (const char*)Bw + (size_t)bn * 64 * ldb_b;

  f32x4 acc[4][2] = {};
  const int KT = K >> 6;

  auto stage = [&](int kt, int bi) {
    char* ld = smem[bi];
    int kb = kt * 128;
#pragma unroll
    for (int c2 = 0; c2 < 4; ++c2) {
      int c = wave + c2 * 4;  // 16 A chunks
      stage_rows(Ab, lda_b, kb, c * 8, ld + c * 1024, lane);
    }
#pragma unroll
    for (int c2 = 0; c2 < 2; ++c2) {
      int c = wave + c2 * 4;  // 8 B chunks
      stage_rows(Bb, ldb_b, kb, c * 8, ld + 16384 + c * 1024, lane);
    }
  };

  stage(0, 0);
  __syncthreads();
  for (int kt = 0; kt < KT; ++kt) {
    int cur = kt & 1;
    if (kt + 1 < KT) stage(kt + 1, cur ^ 1);
    const char* lA = smem[cur];
    const char* lB = smem[cur] + 16384;
#pragma unroll
    for (int kh = 0; kh < 2; ++kh) {
      int kk = kh * 32;
      short8 a[4], b[2];
#pragma unroll
      for (int mi = 0; mi < 4; ++mi) a[mi] = frag_ld(lA, wm * 64 + mi * 16, kk, lane, 128);
#pragma unroll
      for (int nj = 0; nj < 2; ++nj) b[nj] = frag_ld(lB, wn * 32 + nj * 16, kk, lane, 128);
#pragma unroll
      for (int mi = 0; mi < 4; ++mi)
#pragma unroll
        for (int nj = 0; nj < 2; ++nj) acc[mi][nj] = MFMA(a[mi], b[nj], acc[mi][nj]);
    }
    __syncthreads();
  }

#pragma unroll
  for (int mi = 0; mi < 4; ++mi)
#pragma unroll
    for (int nj = 0; nj < 2; ++nj) {
      int col = bn * 64 + wn * 32 + nj * 16 + (lane & 15);
      float bc = bias[col];
#pragma unroll
      for (int ii = 0; ii < 4; ++ii) {
        int row = bm * 128 + wm * 64 + mi * 16 + ((lane >> 4) << 2) + ii;
        float v = acc[mi][nj][ii] + bc;
        if constexpr (MODE == 1) {
          v = v > 0.f ? v : 0.2f * v;
          Ob[row * 512 + col] = __float2bfloat16(v);
        } else {
          // h0_flat[2048,1024].reshape(2,B,H): d=row>>10, b=2*(row&1023)+(col>=512)
          int d = row >> 10, rr = row & 1023;
          int b = 2 * rr + (col >> 9), j = col & 511;
          bf16 vb = __float2bfloat16(v);
          if (d == 0) {
            Of[b * 512 + j] = v;
            Ob[b * 640 + 128 + j] = vb;      // X0[0] h-part, stride 640 off 128
          } else {
            Of2[b * 512 + j] = v;
            Ob2[b * 1024 + 512 + j] = vb;    // X1[0] h-part, stride 1024 off 512
          }
        }
      }
    }
}

// ---------------------------------------------------------------------------
// Fused concat-K GRU step.  A = X[2048][KX+512] = [x | h_prev],
// W = Wcat[1536][KX+512] = [w_ih | w_hh] per row.  Gates r,z accumulate full
// K; gate n split: acc_ni (kt<KX/64, x-part) / acc_nh (h-part).
// BM=64, BN=32/gate, grid (16,32)=512 blocks, 4 waves (2x2).
// ---------------------------------------------------------------------------
template <int KX>
__global__ __launch_bounds__(256) void gru_step(
    const bf16* __restrict__ X, const bf16* __restrict__ Wcat,
    const float* __restrict__ bih, const float* __restrict__ bhh,
    const float* __restrict__ Hpf, const int* __restrict__ act,
    bf16* __restrict__ Fo, int fs, int fo,
    bf16* __restrict__ Hb, int hs, int ho,
    float* __restrict__ Hf) {
  constexpr int KTOT = KX + 512;
  constexpr int KT = KTOT / 64;
  constexpr int NI = KX / 64;
  constexpr int LDB = KTOT * 2;
  __shared__ char smem[2][20480];  // A 8K (64r x 128B) + B 12K (3g x 32r x 128B)
  const int tid = threadIdx.x, lane = tid & 63, wave = tid >> 6;
  const int wm = wave >> 1, wn = wave & 1;
  const int bn = blockIdx.x, bm = blockIdx.y;
  const char* Xb = (const char*)X + (size_t)bm * 64 * LDB;
  const char* Wb = (const char*)Wcat;

  f32x4 ar[2] = {}, az[2] = {}, ani[2] = {}, anh[2] = {};

  auto stage = [&](int kt, int bi) {
    char* ld = smem[bi];
    int kb = kt * 128;
    stage_rows(Xb, LDB, kb, wave * 8, ld + wave * 1024, lane);
    stage_rows(Xb, LDB, kb, (wave + 4) * 8, ld + (wave + 4) * 1024, lane);
#pragma unroll
    for (int c2 = 0; c2 < 3; ++c2) {
      int c = wave + c2 * 4;  // 0..11: gate g=c>>2, sub-chunk cr=c&3
      int g = c >> 2, cr = c & 3;
      stage_rows(Wb + (size_t)(g * 512 + bn * 32) * LDB, LDB, kb, cr * 8,
                 ld + 8192 + c * 1024, lane);
    }
  };

  auto body = [&](int kt, f32x4(&an)[2]) {
    int cur = kt & 1;
    if (kt + 1 < KT) stage(kt + 1, cur ^ 1);
    const char* lA = smem[cur];
    const char* lB = smem[cur] + 8192;
#pragma unroll
    for (int kh = 0; kh < 2; ++kh) {
      int kk = kh * 32;
      short8 a0 = frag_ld(lA, wm * 32, kk, lane, 128);
      short8 a1 = frag_ld(lA, wm * 32 + 16, kk, lane, 128);
      short8 br = frag_ld(lB, wn * 16, kk, lane, 128);
      short8 bz = frag_ld(lB + 4096, wn * 16, kk, lane, 128);
      short8 bnn = frag_ld(lB + 8192, wn * 16, kk, lane, 128);
      ar[0] = MFMA(a0, br, ar[0]);
      ar[1] = MFMA(a1, br, ar[1]);
      az[0] = MFMA(a0, bz, az[0]);
      az[1] = MFMA(a1, bz, az[1]);
      an[0] = MFMA(a0, bnn, an[0]);
      an[1] = MFMA(a1, bnn, an[1]);
    }
    __syncthreads();
  };

  stage(0, 0);
  __syncthreads();
  for (int kt = 0; kt < NI; ++kt) body(kt, ani);
  for (int kt = NI; kt < KT; ++kt) body(kt, anh);

  const int colg = bn * 32 + wn * 16 + (lane & 15);
  const float b_r = bih[colg] + bhh[colg];
  const float b_z = bih[512 + colg] + bhh[512 + colg];
  const float bni = bih[1024 + colg];
  const float bnh = bhh[1024 + colg];
#pragma unroll
  for (int mi = 0; mi < 2; ++mi)
#pragma unroll
    for (int ii = 0; ii < 4; ++ii) {
      int row = bm * 64 + wm * 32 + mi * 16 + ((lane >> 4) << 2) + ii;
      float r_ = sigm(ar[mi][ii] + b_r);
      float z_ = sigm(az[mi][ii] + b_z);
      float n_ = tanhf(ani[mi][ii] + bni + r_ * (anh[mi][ii] + bnh));
      float hp = Hpf[row * 512 + colg];
      float f = (1.f - z_) * n_ + z_ * hp;
      Fo[(size_t)row * fs + fo + colg] = __float2bfloat16(f);
      float hn = act[row] ? f : hp;
      Hb[(size_t)row * hs + ho + colg] = __float2bfloat16(hn);
      Hf[row * 512 + colg] = hn;
    }
}

// ---------------------------------------------------------------------------
// Output head (unchanged from R1, + seq-length write on last step).
// ---------------------------------------------------------------------------
__global__ __launch_bounds__(256) void outproj(
    const bf16* __restrict__ F2, const bf16* __restrict__ Wo,
    const float* __restrict__ bv, const float* __restrict__ bt1,
    const float* __restrict__ bm_, const float* __restrict__ wt2,
    const float* __restrict__ bt2,
    int* __restrict__ active, int* __restrict__ lens,
    float* __restrict__ out, int t, int last) {
  __shared__ char sA[16384];
  __shared__ float red[16][68];
  __shared__ unsigned stopf[16];
  const int tid = threadIdx.x, lane = tid & 63, wave = tid >> 6;
  const int brow = blockIdx.x * 16;

  if (tid < 16) stopf[tid] = 0;

#pragma unroll
  for (int c2 = 0; c2 < 4; ++c2) {
    int c = wave + c2 * 4;  // row 0..15, one 1KB chunk each
    int l = (lane * 16) ^ ((c & 7) << 4);
    gld16((const char*)F2 + (size_t)(brow + c) * 1024 + l, sA + c * 1024);
  }
  __syncthreads();

  f32x4 acc[5] = {};
#pragma unroll 4
  for (int k0 = 0; k0 < 512; k0 += 32) {
    short8 a = frag_ld(sA, 0, k0, lane, 1024);
#pragma unroll
    for (int nf = 0; nf < 5; ++nf) {
      int col = wave * 80 + nf * 16 + (lane & 15);
      short8 b = *(const short8*)((const char*)Wo + (size_t)col * 1024 +
                                  ((k0 + ((lane >> 4) << 3)) << 1));
      acc[nf] = MFMA(a, b, acc[nf]);
    }
  }

#pragma unroll
  for (int nf = 0; nf < 5; ++nf) {
    int col = wave * 80 + nf * 16 + (lane & 15);
#pragma unroll
    for (int ii = 0; ii < 4; ++ii) {
      int r = ((lane >> 4) << 2) + ii;
      int b = brow + r;
      float v = acc[nf][ii];
      if (col < 128) {
        out[(size_t)b * 16384 + t * 128 + col] = sigm(v + bv[col]);
      } else if (col < 192) {
        float x = v + bt1[col - 128];
        red[r][col - 128] = x > 0.f ? x : 0.2f * x;
      } else {
        float m = v + bm_[col - 192];
        out[OFF_M + (size_t)b * 16384 + t * 128 + (col - 192)] = m;
        if (m >= 0.f) atomicOr(&stopf[r], 1u);
      }
    }
  }
  __syncthreads();
  if (tid < 16) {
    int b = brow + tid;
    float s = bt2[0];
    for (int c = 0; c < 64; ++c) s += red[tid][c] * wt2[c];
    out[OFF_U + (size_t)b * 128 + t] = sigm(s);
    int a = active[b];
    int nl = lens[b] + a;
    lens[b] = nl;
    active[b] = a & (stopf[tid] ? 1 : 0);
    if (last) out[OFF_S + b] = (float)nl;
  }
}

extern "C" void kernel_launch(void* const* d_in, const int* in_sizes, int n_in,
                              void* d_out, int out_size, void* d_ws, size_t ws_size,
                              hipStream_t stream) {
  const float* e = (const float*)d_in[0];
  const float* fc1w = (const float*)d_in[1];
  const float* fc1b = (const float*)d_in[2];
  const float* fc2w = (const float*)d_in[3];
  const float* fc2b = (const float*)d_in[4];
  const float* wih0 = (const float*)d_in[5];
  const float* whh0 = (const float*)d_in[6];
  const float* bih0 = (const float*)d_in[7];
  const float* bhh0 = (const float*)d_in[8];
  const float* wih1 = (const float*)d_in[9];
  const float* whh1 = (const float*)d_in[10];
  const float* bih1 = (const float*)d_in[11];
  const float* bhh1 = (const float*)d_in[12];
  const float* wv = (const float*)d_in[13];
  const float* bv = (const float*)d_in[14];
  const float* wt1 = (const float*)d_in[15];
  const float* bt1 = (const float*)d_in[16];
  const float* wt2 = (const float*)d_in[17];
  const float* bt2 = (const float*)d_in[18];
  const float* wm = (const float*)d_in[19];
  const float* bmb = (const float*)d_in[20];
  float* out = (float*)d_out;

  char* p = (char*)d_ws;
  auto carve = [&](size_t bytes) {
    char* r = p;
    p += (bytes + 255) & ~(size_t)255;
    return r;
  };
  bf16* X0[2] = {(bf16*)carve((size_t)2048 * 640 * 2), (bf16*)carve((size_t)2048 * 640 * 2)};
  bf16* X1[2] = {(bf16*)carve((size_t)2048 * 1024 * 2), (bf16*)carve((size_t)2048 * 1024 * 2)};
  bf16* wcat0 = (bf16*)carve((size_t)1536 * 640 * 2);
  bf16* wcat1 = (bf16*)carve((size_t)1536 * 1024 * 2);
  float* hAf[2] = {(float*)carve(2048 * 512 * 4), (float*)carve(2048 * 512 * 4)};
  float* hBf[2] = {(float*)carve(2048 * 512 * 4), (float*)carve(2048 * 512 * 4)};
  bf16* t1_b = (bf16*)carve(2048 * 512 * 2);
  bf16* wfc1b = (bf16*)carve(512 * 128 * 2);
  bf16* wfc2b = (bf16*)carve(1024 * 512 * 2);
  bf16* woutb = (bf16*)carve(320 * 512 * 2);
  bf16* f2b = (bf16*)carve(2048 * 512 * 2);
  int* act = (int*)carve(2048 * 4);
  int* lens = (int*)carve(2048 * 4);

  auto cvt = [&](const float* s, bf16* d, int n) {
    cvtk<<<dim3((n + 255) / 256), dim3(256), 0, stream>>>(s, d, n);
  };
  initk<<<dim3(8), dim3(256), 0, stream>>>(act, lens);
  e_fill<<<dim3(1024), dim3(256), 0, stream>>>(e, X0[0], X0[1]);
  catk<<<dim3((1536 * 640 + 255) / 256), dim3(256), 0, stream>>>(wih0, whh0, wcat0, 128, 1536 * 640);
  catk<<<dim3((1536 * 1024 + 255) / 256), dim3(256), 0, stream>>>(wih1, whh1, wcat1, 512, 1536 * 1024);
  cvt(fc1w, wfc1b, 512 * 128);
  cvt(fc2w, wfc2b, 1024 * 512);
  cvt(wv, woutb, 128 * 512);
  cvt(wt1, woutb + 128 * 512, 64 * 512);
  cvt(wm, woutb + 192 * 512, 128 * 512);

  // t1 = lrelu(e@fc1^T+b) ; A = X0[0] (e part), lda 1280B, B rows 256B
  gemm_plain<1><<<dim3(8, 16), dim3(256), 0, stream>>>(
      X0[0], wfc1b, fc1b, t1_b, nullptr, nullptr, nullptr, 128, 1280, 256);
  // h0 = t1@fc2^T+b -> scatter to hAf[0]/X0[0] and hBf[0]/X1[0]
  gemm_plain<2><<<dim3(16, 16), dim3(256), 0, stream>>>(
      t1_b, wfc2b, fc2b, X0[0], hAf[0], hBf[0], X1[0], 512, 1024, 1024);

  for (int t = 0; t < 128; ++t) {
    int cur = t & 1, nxt = cur ^ 1;
    // layer 0: gates = [e|hA] @ wcat0^T ; f1 -> X1[cur][:,0:512]; hA' -> X0[nxt]
    gru_step<128><<<dim3(16, 32), dim3(256), 0, stream>>>(
        X0[cur], wcat0, bih0, bhh0, hAf[cur], act,
        X1[cur], 1024, 0, X0[nxt], 640, 128, hAf[nxt]);
    // layer 1: gates = [f1|hB] @ wcat1^T ; f2 -> f2b; hB' -> X1[nxt][:,512:]
    gru_step<512><<<dim3(16, 32), dim3(256), 0, stream>>>(
        X1[cur], wcat1, bih1, bhh1, hBf[cur], act,
        f2b, 512, 0, X1[nxt], 1024, 512, hBf[nxt]);
    // heads + stop/active/lens (+ seq write on last step)
    outproj<<<dim3(128), dim3(256), 0, stream>>>(
        f2b, woutb, bv, bt1, bmb, wt2, bt2, act, lens, out, t, t == 127);
  }
}